// Round 8
// baseline (343.378 us; speedup 1.0000x reference)
//
#include <hip/hip_runtime.h>
#include <hip/hip_cooperative_groups.h>

namespace cg = cooperative_groups;

// AttentionGCN on MI355X.
// Math: softmax over axis-of-size-1 == 1 -> h == x (aff_w/cog_w dead).
//   L1: aggregate in 5-dim input space (scatter commutes with W1).
//   L2: apply W2 first, aggregate in 2-dim output space.
// R4: counting-sort -> per-node CSR -> atomic-free gathers (127 -> 76us).
// R5: occupancy push (76 -> 68us).
// R6 FAILED (74us): direct global scatter + returning atomics regressed. Reverted.
// R7: fuse all phases into ONE cooperative kernel with grid.sync() —
//     ~27us of estimated work vs 68us measured => dispatch gaps/tails dominate.

#define NPB     256         // nodes per bin
#define BSHIFT  8
#define BINCAP  6144        // mean edges/bin ~4092, sigma ~64 -> +32 sigma headroom
#define MAXBINS 512
#define FBLK    512         // fused kernel block threads
#define APT     8           // edges per thread in binning phase
#define ROUNDS  3           // BINCAP / (FBLK*4)

__global__ __launch_bounds__(FBLK) void fused_k(
    const int* __restrict__ src, const int* __restrict__ dst,
    const float* __restrict__ x,
    const float* __restrict__ W1, const float* __restrict__ b1,
    const float* __restrict__ W2, const float* __restrict__ b2,
    float* __restrict__ out,
    int* __restrict__ cursor, unsigned int* __restrict__ bpk,
    int* __restrict__ sorted, int* __restrict__ row_start,
    unsigned short* __restrict__ row_cnt,
    float* __restrict__ dinv, float* __restrict__ y8,
    float* __restrict__ g, float* __restrict__ gy,
    int n, int E, int nbins, int nchunks, int ntiles)
{
    cg::grid_group grid = cg::this_grid();
    __shared__ int hist[MAXBINS];
    __shared__ int gbase[MAXBINS];
    __shared__ int cnt[NPB];
    __shared__ int wsum[4];
    __shared__ int srt[BINCAP];
    __shared__ float W1s[320], b1s[64], W2s[128];

    const int t = threadIdx.x;
    const int bid = blockIdx.x;
    const int nb = gridDim.x;

    // ---- phase 0: zero bin cursors (replaces memset dispatch) ----
    if (bid == 0) cursor[t] = 0;          // FBLK == MAXBINS
    grid.sync();

    // ---- phase 1: counting-sort edges into bins, packed (src<<8)|dloc ----
    for (int chunk = bid; chunk < nchunks; chunk += nb) {
        hist[t] = 0;
        __syncthreads();
        int base = chunk * (FBLK * APT);
        int s_[APT], d_[APT], r_[APT];
#pragma unroll
        for (int q = 0; q < APT; ++q) {
            int e = base + q * FBLK + t;
            if (e < E) {
                s_[q] = src[e]; d_[q] = dst[e];
                r_[q] = atomicAdd(&hist[d_[q] >> BSHIFT], 1);   // rank in register
            } else d_[q] = -1;
        }
        __syncthreads();
        if (t < nbins) {
            int h = hist[t];
            gbase[t] = h ? atomicAdd(&cursor[t], h) : 0;        // reserve chunk
        }
        __syncthreads();
#pragma unroll
        for (int q = 0; q < APT; ++q) {
            if (d_[q] >= 0) {
                int b = d_[q] >> BSHIFT;
                int pos = gbase[b] + r_[q];
                if (pos < BINCAP)
                    bpk[(size_t)b * BINCAP + pos] =
                        ((unsigned int)s_[q] << 8) | (unsigned int)(d_[q] & (NPB - 1));
            }
        }
        __syncthreads();   // hist/gbase reused next iteration
    }
    __threadfence();
    grid.sync();

    // ---- phase 2: per bin, node-sorted CSR + dinv + y8 ----
    for (int b = bid; b < nbins; b += nb) {
        if (t < NPB) cnt[t] = 0;
        __syncthreads();
        int m = cursor[b]; if (m > BINCAP) m = BINCAP;
        const unsigned int* pk = bpk + (size_t)b * BINCAP;

        unsigned int pv[ROUNDS][4];
        int rk[ROUNDS][4];
#pragma unroll
        for (int q = 0; q < ROUNDS; ++q) {
            int j0 = q * (FBLK * 4) + t * 4;
            if (j0 + 3 < m) {
                uint4 v = *(const uint4*)(pk + j0);
                pv[q][0] = v.x; pv[q][1] = v.y; pv[q][2] = v.z; pv[q][3] = v.w;
                rk[q][0] = atomicAdd(&cnt[v.x & 255u], 1);
                rk[q][1] = atomicAdd(&cnt[v.y & 255u], 1);
                rk[q][2] = atomicAdd(&cnt[v.z & 255u], 1);
                rk[q][3] = atomicAdd(&cnt[v.w & 255u], 1);
            } else {
#pragma unroll
                for (int qq = 0; qq < 4; ++qq) {
                    int j = j0 + qq;
                    if (j < m) { pv[q][qq] = pk[j]; rk[q][qq] = atomicAdd(&cnt[pv[q][qq] & 255u], 1); }
                    else pv[q][qq] = 0xffffffffu;
                }
            }
        }
        __syncthreads();
        // exclusive block scan of cnt[0..255] by first 256 threads
        int c_ = 0, v = 0;
        int lane = t & 63, w = t >> 6;
        if (t < NPB) {
            c_ = cnt[t];
            v = c_;
#pragma unroll
            for (int dlt = 1; dlt < 64; dlt <<= 1) {
                int u = __shfl_up(v, dlt, 64);
                if (lane >= dlt) v += u;
            }
            if (lane == 63) wsum[w] = v;
        }
        __syncthreads();
        int gb = b * BINCAP;
        if (t < NPB) {
            int wo = 0;
#pragma unroll
            for (int k = 0; k < 4; ++k) if (k < w) wo += wsum[k];
            int offs_t = wo + v - c_;
            cnt[t] = offs_t;                                 // reuse as offset table
            int i = b * NPB + t;
            if (i < n) {
                row_start[i] = gb + offs_t;
                row_cnt[i] = (unsigned short)c_;
                float di = rsqrtf(1.0f + (float)c_);         // ref deg = 1 + indegree
                dinv[i] = di;
#pragma unroll
                for (int k = 0; k < 5; ++k) y8[(size_t)i * 8 + k] = di * x[i * 5 + k];
            }
        }
        __syncthreads();
        // scatter into LDS at unique positions (no atomics)
#pragma unroll
        for (int q = 0; q < ROUNDS; ++q) {
#pragma unroll
            for (int qq = 0; qq < 4; ++qq) {
                unsigned int p = pv[q][qq];
                if (p != 0xffffffffu) {
                    int j0 = q * (FBLK * 4) + t * 4 + qq;
                    if (j0 < m) srt[cnt[p & 255u] + rk[q][qq]] = (int)(p >> 8);
                }
            }
        }
        __syncthreads();
        // coalesced dump of sorted srcs
        for (int j0 = t * 4; j0 + 3 < m; j0 += FBLK * 4)
            *(int4*)(sorted + gb + j0) = *(const int4*)(srt + j0);
        if (t < 4) {
            int start = m & ~3;
            int j = start + t;
            if (j < m) sorted[gb + j] = srt[j];
        }
        __syncthreads();   // cnt/srt reused next iteration
    }
    __threadfence();
    grid.sync();

    // ---- phase 3: 4 lanes per node, aggregate 5-dim + split MLP ----
    if (t < 320) W1s[t] = W1[t];
    else if (t < 384) b1s[t - 320] = b1[t - 320];
    else W2s[t - 384] = W2[t - 384];
    __syncthreads();
    {
        int grp = t >> 2, lane = t & 3;
        for (int tile = bid; tile < ntiles; tile += nb) {
            int i = tile * 128 + grp;
            if (i >= n) continue;
            int st = row_start[i];
            int e  = st + row_cnt[i];
            float a0 = 0.f, a1 = 0.f, a2 = 0.f, a3 = 0.f, a4 = 0.f;
            for (int j = st + lane; j < e; j += 4) {
                int s = sorted[j];
                float4 A = *(const float4*)(y8 + (size_t)s * 8);
                a0 += A.x; a1 += A.y; a2 += A.z; a3 += A.w;
                a4 += y8[(size_t)s * 8 + 4];
            }
            a0 += __shfl_xor(a0, 1); a0 += __shfl_xor(a0, 2);
            a1 += __shfl_xor(a1, 1); a1 += __shfl_xor(a1, 2);
            a2 += __shfl_xor(a2, 1); a2 += __shfl_xor(a2, 2);
            a3 += __shfl_xor(a3, 1); a3 += __shfl_xor(a3, 2);
            a4 += __shfl_xor(a4, 1); a4 += __shfl_xor(a4, 2);
            float di = dinv[i], d2 = di * di;
            float v0 = di * a0 + d2 * x[i * 5 + 0];
            float v1 = di * a1 + d2 * x[i * 5 + 1];
            float v2 = di * a2 + d2 * x[i * 5 + 2];
            float v3 = di * a3 + d2 * x[i * 5 + 3];
            float v4 = di * a4 + d2 * x[i * 5 + 4];
            float g0 = 0.f, g1 = 0.f;
#pragma unroll
            for (int q = 0; q < 16; ++q) {
                int jj = lane + q * 4;
                float h = b1s[jj];
                h = fmaf(v0, W1s[0 * 64 + jj], h);
                h = fmaf(v1, W1s[1 * 64 + jj], h);
                h = fmaf(v2, W1s[2 * 64 + jj], h);
                h = fmaf(v3, W1s[3 * 64 + jj], h);
                h = fmaf(v4, W1s[4 * 64 + jj], h);
                h = fmaxf(h, 0.f);
                g0 = fmaf(h, W2s[2 * jj], g0);
                g1 = fmaf(h, W2s[2 * jj + 1], g1);
            }
            g0 += __shfl_xor(g0, 1); g0 += __shfl_xor(g0, 2);
            g1 += __shfl_xor(g1, 1); g1 += __shfl_xor(g1, 2);
            if (lane == 0) {
                g[i * 2] = g0;       g[i * 2 + 1] = g1;
                gy[i * 2] = di * g0; gy[i * 2 + 1] = di * g1;
            }
        }
    }
    __threadfence();
    grid.sync();

    // ---- phase 4: 4 lanes per node, aggregate 2-dim + bias + log_softmax ----
    {
        int grp = t >> 2, lane = t & 3;
        float B0 = b2[0], B1 = b2[1];
        for (int tile = bid; tile < ntiles; tile += nb) {
            int i = tile * 128 + grp;
            if (i >= n) continue;
            int st = row_start[i];
            int e  = st + row_cnt[i];
            float t0 = 0.f, t1 = 0.f;
            for (int j = st + lane; j < e; j += 4) {
                int s = sorted[j];
                float2 vv = *(const float2*)(gy + (size_t)s * 2);
                t0 += vv.x; t1 += vv.y;
            }
            t0 += __shfl_xor(t0, 1); t0 += __shfl_xor(t0, 2);
            t1 += __shfl_xor(t1, 1); t1 += __shfl_xor(t1, 2);
            if (lane == 0) {
                float di = dinv[i], d2 = di * di;
                float o0 = di * t0 + d2 * g[i * 2]     + B0;
                float o1 = di * t1 + d2 * g[i * 2 + 1] + B1;
                float mx = fmaxf(o0, o1);
                float lse = mx + logf(expf(o0 - mx) + expf(o1 - mx));
                out[i * 2]     = o0 - lse;
                out[i * 2 + 1] = o1 - lse;
            }
        }
    }
}

// ================= fallback: proven R5 4-kernel path (68.3us) ==================
#define ABLK    512
#define BBLK    512

__global__ __launch_bounds__(ABLK) void binA_k(const int* __restrict__ src, const int* __restrict__ dst,
                                               int E, int nbins, int* __restrict__ cursor,
                                               unsigned int* __restrict__ bpk) {
    __shared__ int hist[MAXBINS];
    __shared__ int gbase[MAXBINS];
    int t = threadIdx.x;
    hist[t] = 0;
    __syncthreads();
    int base = blockIdx.x * (ABLK * APT);
    int s_[APT], d_[APT], r_[APT];
#pragma unroll
    for (int q = 0; q < APT; ++q) {
        int e = base + q * ABLK + t;
        if (e < E) {
            s_[q] = src[e]; d_[q] = dst[e];
            r_[q] = atomicAdd(&hist[d_[q] >> BSHIFT], 1);
        } else d_[q] = -1;
    }
    __syncthreads();
    if (t < nbins) {
        int h = hist[t];
        gbase[t] = h ? atomicAdd(&cursor[t], h) : 0;
    }
    __syncthreads();
#pragma unroll
    for (int q = 0; q < APT; ++q) {
        if (d_[q] >= 0) {
            int b = d_[q] >> BSHIFT;
            int pos = gbase[b] + r_[q];
            if (pos < BINCAP)
                bpk[(size_t)b * BINCAP + pos] = ((unsigned int)s_[q] << 8) | (unsigned int)(d_[q] & (NPB - 1));
        }
    }
}

__global__ __launch_bounds__(BBLK) void build_k(const int* __restrict__ cursor,
                                                const unsigned int* __restrict__ bpk,
                                                const float* __restrict__ x,
                                                int* __restrict__ sorted,
                                                int* __restrict__ row_start,
                                                unsigned short* __restrict__ row_cnt,
                                                float* __restrict__ dinv, float* __restrict__ y8, int n) {
    __shared__ int cnt[NPB];
    __shared__ int offs[NPB];
    __shared__ int srt[BINCAP];
    __shared__ int wsum[4];
    int b = blockIdx.x, t = threadIdx.x;
    if (t < NPB) cnt[t] = 0;
    __syncthreads();
    int m = cursor[b]; if (m > BINCAP) m = BINCAP;
    const unsigned int* pk = bpk + (size_t)b * BINCAP;

    unsigned int pv[ROUNDS][4];
    int rk[ROUNDS][4];
#pragma unroll
    for (int q = 0; q < ROUNDS; ++q) {
        int j0 = q * (BBLK * 4) + t * 4;
        if (j0 + 3 < m) {
            uint4 v = *(const uint4*)(pk + j0);
            pv[q][0] = v.x; pv[q][1] = v.y; pv[q][2] = v.z; pv[q][3] = v.w;
            rk[q][0] = atomicAdd(&cnt[v.x & 255u], 1);
            rk[q][1] = atomicAdd(&cnt[v.y & 255u], 1);
            rk[q][2] = atomicAdd(&cnt[v.z & 255u], 1);
            rk[q][3] = atomicAdd(&cnt[v.w & 255u], 1);
        } else {
#pragma unroll
            for (int qq = 0; qq < 4; ++qq) {
                int j = j0 + qq;
                if (j < m) { pv[q][qq] = pk[j]; rk[q][qq] = atomicAdd(&cnt[pv[q][qq] & 255u], 1); }
                else pv[q][qq] = 0xffffffffu;
            }
        }
    }
    __syncthreads();
    int c_ = 0, v = 0;
    int lane = t & 63, w = t >> 6;
    if (t < NPB) {
        c_ = cnt[t];
        v = c_;
#pragma unroll
        for (int dlt = 1; dlt < 64; dlt <<= 1) {
            int u = __shfl_up(v, dlt, 64);
            if (lane >= dlt) v += u;
        }
        if (lane == 63) wsum[w] = v;
    }
    __syncthreads();
    if (t < NPB) {
        int wo = 0;
#pragma unroll
        for (int k = 0; k < 4; ++k) if (k < w) wo += wsum[k];
        offs[t] = wo + v - c_;
    }
    __syncthreads();
#pragma unroll
    for (int q = 0; q < ROUNDS; ++q) {
#pragma unroll
        for (int qq = 0; qq < 4; ++qq) {
            unsigned int p = pv[q][qq];
            if (p != 0xffffffffu) {
                int j0 = q * (BBLK * 4) + t * 4 + qq;
                if (j0 < m) srt[offs[p & 255u] + rk[q][qq]] = (int)(p >> 8);
            }
        }
    }
    __syncthreads();
    int gb = b * BINCAP;
    for (int j0 = t * 4; j0 + 3 < m; j0 += BBLK * 4)
        *(int4*)(sorted + gb + j0) = *(const int4*)(srt + j0);
    if (t < 4) {
        int start = m & ~3;
        int j = start + t;
        if (j < m) sorted[gb + j] = srt[j];
    }
    int i = b * NPB + t;
    if (t < NPB && i < n) {
        row_start[i] = gb + offs[t];
        row_cnt[i] = (unsigned short)c_;
        float di = rsqrtf(1.0f + (float)c_);
        dinv[i] = di;
#pragma unroll
        for (int k = 0; k < 5; ++k) y8[(size_t)i * 8 + k] = di * x[i * 5 + k];
    }
}

__global__ __launch_bounds__(256) void gath1_mlp_k(const int* __restrict__ sorted,
                                                   const int* __restrict__ row_start,
                                                   const unsigned short* __restrict__ row_cnt,
                                                   const float* __restrict__ x, const float* __restrict__ y8,
                                                   const float* __restrict__ dinv,
                                                   const float* __restrict__ W1, const float* __restrict__ b1,
                                                   const float* __restrict__ W2,
                                                   float* __restrict__ g, float* __restrict__ gy, int n) {
    __shared__ float W1s[320], b1s[64], W2s[128];
    int t = threadIdx.x;
    { int j = t; if (j < 320) W1s[j] = W1[j]; j = t + 256; if (j < 320) W1s[j] = W1[j]; }
    if (t < 64) b1s[t] = b1[t];
    if (t >= 64 && t < 192) W2s[t - 64] = W2[t - 64];
    __syncthreads();
    int grp = t >> 2, lane = t & 3;
    int i = blockIdx.x * 64 + grp;
    if (i >= n) return;
    int st = row_start[i];
    int e  = st + row_cnt[i];
    float a0 = 0.f, a1 = 0.f, a2 = 0.f, a3 = 0.f, a4 = 0.f;
    for (int j = st + lane; j < e; j += 4) {
        int s = sorted[j];
        float4 A = *(const float4*)(y8 + (size_t)s * 8);
        a0 += A.x; a1 += A.y; a2 += A.z; a3 += A.w;
        a4 += y8[(size_t)s * 8 + 4];
    }
    a0 += __shfl_xor(a0, 1); a0 += __shfl_xor(a0, 2);
    a1 += __shfl_xor(a1, 1); a1 += __shfl_xor(a1, 2);
    a2 += __shfl_xor(a2, 1); a2 += __shfl_xor(a2, 2);
    a3 += __shfl_xor(a3, 1); a3 += __shfl_xor(a3, 2);
    a4 += __shfl_xor(a4, 1); a4 += __shfl_xor(a4, 2);
    float di = dinv[i], d2 = di * di;
    float v0 = di * a0 + d2 * x[i * 5 + 0];
    float v1 = di * a1 + d2 * x[i * 5 + 1];
    float v2 = di * a2 + d2 * x[i * 5 + 2];
    float v3 = di * a3 + d2 * x[i * 5 + 3];
    float v4 = di * a4 + d2 * x[i * 5 + 4];
    float g0 = 0.f, g1 = 0.f;
#pragma unroll
    for (int q = 0; q < 16; ++q) {
        int jj = lane + q * 4;
        float h = b1s[jj];
        h = fmaf(v0, W1s[0 * 64 + jj], h);
        h = fmaf(v1, W1s[1 * 64 + jj], h);
        h = fmaf(v2, W1s[2 * 64 + jj], h);
        h = fmaf(v3, W1s[3 * 64 + jj], h);
        h = fmaf(v4, W1s[4 * 64 + jj], h);
        h = fmaxf(h, 0.f);
        g0 = fmaf(h, W2s[2 * jj], g0);
        g1 = fmaf(h, W2s[2 * jj + 1], g1);
    }
    g0 += __shfl_xor(g0, 1); g0 += __shfl_xor(g0, 2);
    g1 += __shfl_xor(g1, 1); g1 += __shfl_xor(g1, 2);
    if (lane == 0) {
        g[i * 2] = g0;       g[i * 2 + 1] = g1;
        gy[i * 2] = di * g0; gy[i * 2 + 1] = di * g1;
    }
}

__global__ __launch_bounds__(256) void gath2_final_k(const int* __restrict__ sorted,
                                                     const int* __restrict__ row_start,
                                                     const unsigned short* __restrict__ row_cnt,
                                                     const float* __restrict__ g, const float* __restrict__ gy,
                                                     const float* __restrict__ dinv,
                                                     const float* __restrict__ b2,
                                                     float* __restrict__ out, int n) {
    int t = threadIdx.x;
    int grp = t >> 2, lane = t & 3;
    int i = blockIdx.x * 64 + grp;
    if (i >= n) return;
    int st = row_start[i];
    int e  = st + row_cnt[i];
    float t0 = 0.f, t1 = 0.f;
    for (int j = st + lane; j < e; j += 4) {
        int s = sorted[j];
        float2 v = *(const float2*)(gy + (size_t)s * 2);
        t0 += v.x; t1 += v.y;
    }
    t0 += __shfl_xor(t0, 1); t0 += __shfl_xor(t0, 2);
    t1 += __shfl_xor(t1, 1); t1 += __shfl_xor(t1, 2);
    if (lane == 0) {
        float di = dinv[i], d2 = di * di;
        float o0 = di * t0 + d2 * g[i * 2]     + b2[0];
        float o1 = di * t1 + d2 * g[i * 2 + 1] + b2[1];
        float mx = fmaxf(o0, o1);
        float lse = mx + logf(expf(o0 - mx) + expf(o1 - mx));
        out[i * 2]     = o0 - lse;
        out[i * 2 + 1] = o1 - lse;
    }
}
// ================================================================================

extern "C" void kernel_launch(void* const* d_in, const int* in_sizes, int n_in,
                              void* d_out, int out_size, void* d_ws, size_t ws_size,
                              hipStream_t stream) {
    const int*   src0 = (const int*)d_in[1];
    const float* x  = (const float*)d_in[0];
    const float* W1 = (const float*)d_in[4];
    const float* b1 = (const float*)d_in[5];
    const float* W2 = (const float*)d_in[6];
    const float* b2 = (const float*)d_in[7];
    float* out = (float*)d_out;

    const int n = in_sizes[0] / 5;
    const int E = in_sizes[1] / 2;
    const int* src = src0;
    const int* dst = src0 + E;

    const int nbins = (n + NPB - 1) >> BSHIFT;
    size_t need = (size_t)MAXBINS * 4 + (size_t)nbins * BINCAP * 8 +
                  (size_t)n * (4 + 2 + 4 + 32 + 8 + 8) + 64;

    if (!(nbins <= MAXBINS && n < (1 << 23) && ws_size >= need)) return;  // shape contract

    int* cursor = (int*)d_ws;
    unsigned int* bpk = (unsigned int*)(cursor + MAXBINS);
    int* sorted = (int*)(bpk + (size_t)nbins * BINCAP);
    int* row_start = sorted + (size_t)nbins * BINCAP;
    unsigned short* row_cnt = (unsigned short*)(row_start + n);
    float* dinv = (float*)(row_cnt + ((n + 1) & ~1));
    float* y8 = dinv + n;
    float* g  = y8 + 8 * (size_t)n;
    float* gy = g + 2 * (size_t)n;

    int nchunks = (E + FBLK * APT - 1) / (FBLK * APT);
    int ntiles  = (n + 127) / 128;

    // try the fused cooperative path
    bool fused_ok = false;
    int occ = 0, ncu = 0;
    hipError_t e1 = hipOccupancyMaxActiveBlocksPerMultiprocessor(&occ, fused_k, FBLK, 0);
    hipError_t e2 = hipDeviceGetAttribute(&ncu, hipDeviceAttributeMultiprocessorCount, 0);
    if (e1 == hipSuccess && e2 == hipSuccess && occ > 0 && ncu > 0) {
        int work = nchunks;
        if (nbins > work)  work = nbins;
        if (ntiles > work) work = ntiles;
        int grid = occ * ncu;
        if (grid > work) grid = work;
        void* args[] = { (void*)&src, (void*)&dst, (void*)&x, (void*)&W1, (void*)&b1,
                         (void*)&W2, (void*)&b2, (void*)&out,
                         (void*)&cursor, (void*)&bpk, (void*)&sorted, (void*)&row_start,
                         (void*)&row_cnt, (void*)&dinv, (void*)&y8, (void*)&g, (void*)&gy,
                         (void*)&n, (void*)&E, (void*)&nbins, (void*)&nchunks, (void*)&ntiles };
        hipError_t le = hipLaunchCooperativeKernel((const void*)fused_k, dim3(grid), dim3(FBLK),
                                                   args, 0, stream);
        fused_ok = (le == hipSuccess);
    }

    if (!fused_ok) {
        // proven R5 4-kernel path
        hipMemsetAsync(cursor, 0, MAXBINS * sizeof(int), stream);
        int ablocks = (E + ABLK * APT - 1) / (ABLK * APT);
        binA_k<<<ablocks, ABLK, 0, stream>>>(src, dst, E, nbins, cursor, bpk);
        build_k<<<nbins, BBLK, 0, stream>>>(cursor, bpk, x, sorted, row_start, row_cnt, dinv, y8, n);
        int g64 = (n + 63) / 64;
        gath1_mlp_k<<<g64, 256, 0, stream>>>(sorted, row_start, row_cnt, x, y8, dinv, W1, b1, W2, g, gy, n);
        gath2_final_k<<<g64, 256, 0, stream>>>(sorted, row_start, row_cnt, g, gy, dinv, b2, out, n);
    }
}

// Round 9
// 66.297 us; speedup vs baseline: 5.1794x; 5.1794x over previous
//
#include <hip/hip_runtime.h>

// AttentionGCN on MI355X.
// Math: softmax over axis-of-size-1 == 1 -> h == x (aff_w/cog_w dead).
//   L1: aggregate in 5-dim input space (scatter commutes with W1).
//   L2: apply W2 first, aggregate in 2-dim output space.
// R4: counting-sort -> per-node CSR -> atomic-free gathers (127 -> 76us).
// R5: occupancy push (76 -> 68us).  R6 FAILED (74us). R7 cooperative fusion
// FAILED HARD (343us: grid.sync spin ~70us each at 6200 waves). Reverted to R5.
// R8: algebraic trims: v = di*(a + y8self) kills x-reads in gath1;
//     o = di*(t + gy_self) + b2 kills the g array entirely; int4 edge loads.

#define NPB     256         // nodes per bin
#define BSHIFT  8
#define BINCAP  6144        // mean edges/bin ~4092, sigma ~64 -> +32 sigma headroom
#define MAXBINS 512
#define ABLK    512         // binA block threads
#define APT     8           // edges per thread in binA (2 rounds of int4)
#define BBLK    512         // build block threads
#define ROUNDS  3           // BINCAP / (BBLK*4)

// ---- pass 1: counting-sort edges into 256-node bins, packed (src<<8)|dloc ----
__global__ __launch_bounds__(ABLK) void binA_k(const int* __restrict__ src, const int* __restrict__ dst,
                                               int E, int nbins, int* __restrict__ cursor,
                                               unsigned int* __restrict__ bpk) {
    __shared__ int hist[MAXBINS];
    __shared__ int gbase[MAXBINS];
    int t = threadIdx.x;
    hist[t] = 0;                       // MAXBINS == ABLK
    __syncthreads();
    int base = blockIdx.x * (ABLK * APT);
    int s_[APT], d_[APT], r_[APT];
#pragma unroll
    for (int r = 0; r < APT / 4; ++r) {
        int j0 = base + (r * ABLK + t) * 4;
        if (j0 + 3 < E) {
            int4 s4 = *(const int4*)(src + j0);
            int4 d4 = *(const int4*)(dst + j0);
            s_[r * 4 + 0] = s4.x; s_[r * 4 + 1] = s4.y; s_[r * 4 + 2] = s4.z; s_[r * 4 + 3] = s4.w;
            d_[r * 4 + 0] = d4.x; d_[r * 4 + 1] = d4.y; d_[r * 4 + 2] = d4.z; d_[r * 4 + 3] = d4.w;
#pragma unroll
            for (int q = 0; q < 4; ++q)
                r_[r * 4 + q] = atomicAdd(&hist[d_[r * 4 + q] >> BSHIFT], 1);
        } else {
#pragma unroll
            for (int q = 0; q < 4; ++q) {
                int e = j0 + q;
                if (e < E) {
                    s_[r * 4 + q] = src[e]; d_[r * 4 + q] = dst[e];
                    r_[r * 4 + q] = atomicAdd(&hist[d_[r * 4 + q] >> BSHIFT], 1);
                } else d_[r * 4 + q] = -1;
            }
        }
    }
    __syncthreads();
    if (t < nbins) {
        int h = hist[t];
        gbase[t] = h ? atomicAdd(&cursor[t], h) : 0;
    }
    __syncthreads();
#pragma unroll
    for (int q = 0; q < APT; ++q) {
        if (d_[q] >= 0) {
            int b = d_[q] >> BSHIFT;
            int pos = gbase[b] + r_[q];
            if (pos < BINCAP)
                bpk[(size_t)b * BINCAP + pos] = ((unsigned int)s_[q] << 8) | (unsigned int)(d_[q] & (NPB - 1));
        }
    }
}

// ---- pass 2: per bin, build node-sorted CSR + dinv + y8 (rank-in-register) ----
__global__ __launch_bounds__(BBLK) void build_k(const int* __restrict__ cursor,
                                                const unsigned int* __restrict__ bpk,
                                                const float* __restrict__ x,
                                                int* __restrict__ sorted,
                                                int* __restrict__ row_start,
                                                unsigned short* __restrict__ row_cnt,
                                                float* __restrict__ dinv, float* __restrict__ y8, int n) {
    __shared__ int cnt[NPB];
    __shared__ int offs[NPB];
    __shared__ int srt[BINCAP];
    __shared__ int wsum[4];
    int b = blockIdx.x, t = threadIdx.x;
    if (t < NPB) cnt[t] = 0;
    __syncthreads();
    int m = cursor[b]; if (m > BINCAP) m = BINCAP;
    const unsigned int* pk = bpk + (size_t)b * BINCAP;

    unsigned int pv[ROUNDS][4];
    int rk[ROUNDS][4];
#pragma unroll
    for (int q = 0; q < ROUNDS; ++q) {
        int j0 = q * (BBLK * 4) + t * 4;
        if (j0 + 3 < m) {
            uint4 v = *(const uint4*)(pk + j0);
            pv[q][0] = v.x; pv[q][1] = v.y; pv[q][2] = v.z; pv[q][3] = v.w;
            rk[q][0] = atomicAdd(&cnt[v.x & 255u], 1);
            rk[q][1] = atomicAdd(&cnt[v.y & 255u], 1);
            rk[q][2] = atomicAdd(&cnt[v.z & 255u], 1);
            rk[q][3] = atomicAdd(&cnt[v.w & 255u], 1);
        } else {
#pragma unroll
            for (int qq = 0; qq < 4; ++qq) {
                int j = j0 + qq;
                if (j < m) { pv[q][qq] = pk[j]; rk[q][qq] = atomicAdd(&cnt[pv[q][qq] & 255u], 1); }
                else pv[q][qq] = 0xffffffffu;
            }
        }
    }
    __syncthreads();
    int c_ = 0, v = 0;
    int lane = t & 63, w = t >> 6;
    if (t < NPB) {
        c_ = cnt[t];
        v = c_;
#pragma unroll
        for (int dlt = 1; dlt < 64; dlt <<= 1) {
            int u = __shfl_up(v, dlt, 64);
            if (lane >= dlt) v += u;
        }
        if (lane == 63) wsum[w] = v;
    }
    __syncthreads();
    if (t < NPB) {
        int wo = 0;
#pragma unroll
        for (int k = 0; k < 4; ++k) if (k < w) wo += wsum[k];
        offs[t] = wo + v - c_;
    }
    __syncthreads();
#pragma unroll
    for (int q = 0; q < ROUNDS; ++q) {
#pragma unroll
        for (int qq = 0; qq < 4; ++qq) {
            unsigned int p = pv[q][qq];
            if (p != 0xffffffffu) {
                int j0 = q * (BBLK * 4) + t * 4 + qq;
                if (j0 < m) srt[offs[p & 255u] + rk[q][qq]] = (int)(p >> 8);
            }
        }
    }
    __syncthreads();
    int gb = b * BINCAP;
    for (int j0 = t * 4; j0 + 3 < m; j0 += BBLK * 4)
        *(int4*)(sorted + gb + j0) = *(const int4*)(srt + j0);
    if (t < 4) {
        int start = m & ~3;
        int j = start + t;
        if (j < m) sorted[gb + j] = srt[j];
    }
    int i = b * NPB + t;
    if (t < NPB && i < n) {
        row_start[i] = gb + offs[t];
        row_cnt[i] = (unsigned short)c_;
        float di = rsqrtf(1.0f + (float)c_);    // ref deg = 1 + indegree
        dinv[i] = di;
#pragma unroll
        for (int k = 0; k < 5; ++k) y8[(size_t)i * 8 + k] = di * x[i * 5 + k];
    }
}

// ---- pass 3: 4 lanes per node, aggregate 5-dim + split MLP ----
// v = di*(sum_in y8[s] + y8[i])  (since di^2*x = di*y8self); writes only gy.
__global__ __launch_bounds__(256) void gath1_mlp_k(const int* __restrict__ sorted,
                                                   const int* __restrict__ row_start,
                                                   const unsigned short* __restrict__ row_cnt,
                                                   const float* __restrict__ y8,
                                                   const float* __restrict__ dinv,
                                                   const float* __restrict__ W1, const float* __restrict__ b1,
                                                   const float* __restrict__ W2,
                                                   float* __restrict__ gy, int n) {
    __shared__ float W1s[320], b1s[64], W2s[128];
    int t = threadIdx.x;
    { int j = t; if (j < 320) W1s[j] = W1[j]; j = t + 256; if (j < 320) W1s[j] = W1[j]; }
    if (t < 64) b1s[t] = b1[t];
    if (t >= 64 && t < 192) W2s[t - 64] = W2[t - 64];
    __syncthreads();
    int grp = t >> 2, lane = t & 3;
    int i = blockIdx.x * 64 + grp;
    if (i >= n) return;
    int st = row_start[i];
    int e  = st + row_cnt[i];
    float a0 = 0.f, a1 = 0.f, a2 = 0.f, a3 = 0.f, a4 = 0.f;
    for (int j = st + lane; j < e; j += 4) {
        int s = sorted[j];
        float4 A = *(const float4*)(y8 + (size_t)s * 8);
        a0 += A.x; a1 += A.y; a2 += A.z; a3 += A.w;
        a4 += y8[(size_t)s * 8 + 4];
    }
    a0 += __shfl_xor(a0, 1); a0 += __shfl_xor(a0, 2);
    a1 += __shfl_xor(a1, 1); a1 += __shfl_xor(a1, 2);
    a2 += __shfl_xor(a2, 1); a2 += __shfl_xor(a2, 2);
    a3 += __shfl_xor(a3, 1); a3 += __shfl_xor(a3, 2);
    a4 += __shfl_xor(a4, 1); a4 += __shfl_xor(a4, 2);
    // self term: di^2 * x[i] = di * y8[i]  ->  v = di * (a + y8[i])
    float4 S = *(const float4*)(y8 + (size_t)i * 8);
    float s4 = y8[(size_t)i * 8 + 4];
    float di = dinv[i];
    float v0 = di * (a0 + S.x);
    float v1 = di * (a1 + S.y);
    float v2 = di * (a2 + S.z);
    float v3 = di * (a3 + S.w);
    float v4 = di * (a4 + s4);
    float g0 = 0.f, g1 = 0.f;
#pragma unroll
    for (int q = 0; q < 16; ++q) {
        int jj = lane + q * 4;
        float h = b1s[jj];
        h = fmaf(v0, W1s[0 * 64 + jj], h);
        h = fmaf(v1, W1s[1 * 64 + jj], h);
        h = fmaf(v2, W1s[2 * 64 + jj], h);
        h = fmaf(v3, W1s[3 * 64 + jj], h);
        h = fmaf(v4, W1s[4 * 64 + jj], h);
        h = fmaxf(h, 0.f);
        g0 = fmaf(h, W2s[2 * jj], g0);
        g1 = fmaf(h, W2s[2 * jj + 1], g1);
    }
    g0 += __shfl_xor(g0, 1); g0 += __shfl_xor(g0, 2);
    g1 += __shfl_xor(g1, 1); g1 += __shfl_xor(g1, 2);
    if (lane == 0) {
        gy[i * 2] = di * g0; gy[i * 2 + 1] = di * g1;
    }
}

// ---- pass 4: 4 lanes per node, aggregate 2-dim + bias + log_softmax ----
// o = di*(sum_in gy[s] + gy[i]) + b2   (since di^2*g = di*gy_self)
__global__ __launch_bounds__(256) void gath2_final_k(const int* __restrict__ sorted,
                                                     const int* __restrict__ row_start,
                                                     const unsigned short* __restrict__ row_cnt,
                                                     const float* __restrict__ gy,
                                                     const float* __restrict__ dinv,
                                                     const float* __restrict__ b2,
                                                     float* __restrict__ out, int n) {
    int t = threadIdx.x;
    int grp = t >> 2, lane = t & 3;
    int i = blockIdx.x * 64 + grp;
    if (i >= n) return;
    int st = row_start[i];
    int e  = st + row_cnt[i];
    float t0 = 0.f, t1 = 0.f;
    for (int j = st + lane; j < e; j += 4) {
        int s = sorted[j];
        float2 v = *(const float2*)(gy + (size_t)s * 2);
        t0 += v.x; t1 += v.y;
    }
    t0 += __shfl_xor(t0, 1); t0 += __shfl_xor(t0, 2);
    t1 += __shfl_xor(t1, 1); t1 += __shfl_xor(t1, 2);
    if (lane == 0) {
        float2 Sg = *(const float2*)(gy + (size_t)i * 2);
        float di = dinv[i];
        float o0 = di * (t0 + Sg.x) + b2[0];
        float o1 = di * (t1 + Sg.y) + b2[1];
        float mx = fmaxf(o0, o1);
        float lse = mx + logf(expf(o0 - mx) + expf(o1 - mx));
        out[i * 2]     = o0 - lse;
        out[i * 2 + 1] = o1 - lse;
    }
}

// ---------------- fallback (R1, proven) if ws too small / shape unexpected ------
#define CAP 48
__global__ void fill_k(const int* __restrict__ src, const int* __restrict__ dst,
                       int E, int n, int* __restrict__ cnt, int* __restrict__ bucket) {
    int e = blockIdx.x * blockDim.x + threadIdx.x;
    if (e >= E) return;
    int s = src[e], d = dst[e];
    int slot = atomicAdd(&cnt[d], 1);
    if (slot < CAP) bucket[slot * n + d] = s;
}
__global__ void dinv_y_k(const float* __restrict__ x, const int* __restrict__ cnt,
                         float* __restrict__ dinv, float* __restrict__ y, int n) {
    int i = blockIdx.x * blockDim.x + threadIdx.x;
    if (i >= n) return;
    float di = rsqrtf(1.0f + (float)cnt[i]);
    dinv[i] = di;
#pragma unroll
    for (int k = 0; k < 5; ++k) y[i * 5 + k] = di * x[i * 5 + k];
}
__global__ void gather1_mlp_k(const float* __restrict__ x, const float* __restrict__ y,
                              const float* __restrict__ dinv, const int* __restrict__ cnt,
                              const int* __restrict__ bucket, int n,
                              const float* __restrict__ W1, const float* __restrict__ b1,
                              const float* __restrict__ W2,
                              float* __restrict__ g, float* __restrict__ gy) {
    __shared__ float W1s[320]; __shared__ float b1s[64]; __shared__ float W2s[128];
    int t = threadIdx.x;
    for (int j = t; j < 320; j += blockDim.x) W1s[j] = W1[j];
    if (t < 64) { b1s[t] = b1[t]; W2s[2 * t] = W2[2 * t]; W2s[2 * t + 1] = W2[2 * t + 1]; }
    __syncthreads();
    int i = blockIdx.x * blockDim.x + t;
    if (i >= n) return;
    int c = cnt[i]; if (c > CAP) c = CAP;
    float a0 = 0, a1 = 0, a2 = 0, a3 = 0, a4 = 0;
    for (int j = 0; j < c; ++j) {
        int s = bucket[j * n + i];
        const float* ys = y + s * 5;
        a0 += ys[0]; a1 += ys[1]; a2 += ys[2]; a3 += ys[3]; a4 += ys[4];
    }
    float di = dinv[i], d2 = di * di;
    float v0 = di * a0 + d2 * x[i * 5 + 0], v1 = di * a1 + d2 * x[i * 5 + 1];
    float v2 = di * a2 + d2 * x[i * 5 + 2], v3 = di * a3 + d2 * x[i * 5 + 3];
    float v4 = di * a4 + d2 * x[i * 5 + 4];
    float g0 = 0.f, g1 = 0.f;
#pragma unroll
    for (int j = 0; j < 64; ++j) {
        float h = b1s[j];
        h = fmaf(v0, W1s[j], h); h = fmaf(v1, W1s[64 + j], h); h = fmaf(v2, W1s[128 + j], h);
        h = fmaf(v3, W1s[192 + j], h); h = fmaf(v4, W1s[256 + j], h);
        h = fmaxf(h, 0.f);
        g0 = fmaf(h, W2s[2 * j], g0); g1 = fmaf(h, W2s[2 * j + 1], g1);
    }
    g[i * 2] = g0; g[i * 2 + 1] = g1;
    gy[i * 2] = di * g0; gy[i * 2 + 1] = di * g1;
}
__global__ void gather2_final_fb_k(const float* __restrict__ g, const float* __restrict__ gy,
                                   const float* __restrict__ dinv, const int* __restrict__ cnt,
                                   const int* __restrict__ bucket, int n,
                                   const float* __restrict__ b2, float* __restrict__ out) {
    int i = blockIdx.x * blockDim.x + threadIdx.x;
    if (i >= n) return;
    int c = cnt[i]; if (c > CAP) c = CAP;
    float t0 = 0.f, t1 = 0.f;
    for (int j = 0; j < c; ++j) {
        int s = bucket[j * n + i];
        t0 += gy[s * 2]; t1 += gy[s * 2 + 1];
    }
    float di = dinv[i], d2 = di * di;
    float o0 = di * t0 + d2 * g[i * 2] + b2[0];
    float o1 = di * t1 + d2 * g[i * 2 + 1] + b2[1];
    float mx = fmaxf(o0, o1);
    float lse = mx + logf(expf(o0 - mx) + expf(o1 - mx));
    out[i * 2] = o0 - lse; out[i * 2 + 1] = o1 - lse;
}
// --------------------------------------------------------------------------------

extern "C" void kernel_launch(void* const* d_in, const int* in_sizes, int n_in,
                              void* d_out, int out_size, void* d_ws, size_t ws_size,
                              hipStream_t stream) {
    const float* x  = (const float*)d_in[0];
    const int*   ei = (const int*)d_in[1];
    const float* W1 = (const float*)d_in[4];
    const float* b1 = (const float*)d_in[5];
    const float* W2 = (const float*)d_in[6];
    const float* b2 = (const float*)d_in[7];
    float* out = (float*)d_out;

    const int n = in_sizes[0] / 5;
    const int E = in_sizes[1] / 2;
    const int* src = ei;
    const int* dst = ei + E;

    const int nbins = (n + NPB - 1) >> BSHIFT;
    // layout: cursor[MAXBINS] | bpk[nbins*BINCAP] u32 | sorted[nbins*BINCAP] int |
    //         row_start[n] int | row_cnt[n] u16(pad) | dinv[n] | y8[8n] | gy[2n]
    size_t need = (size_t)MAXBINS * 4 + (size_t)nbins * BINCAP * 8 +
                  (size_t)n * (4 + 2 + 4 + 32 + 8) + 64;

    if (nbins <= MAXBINS && n < (1 << 24) && ws_size >= need) {
        int* cursor = (int*)d_ws;
        unsigned int* bpk = (unsigned int*)(cursor + MAXBINS);
        int* sorted = (int*)(bpk + (size_t)nbins * BINCAP);
        int* row_start = sorted + (size_t)nbins * BINCAP;
        unsigned short* row_cnt = (unsigned short*)(row_start + n);
        float* dinv = (float*)(row_cnt + ((n + 1) & ~1));
        float* y8 = dinv + n;
        float* gy = y8 + 8 * (size_t)n;

        hipMemsetAsync(cursor, 0, MAXBINS * sizeof(int), stream);
        int ablocks = (E + ABLK * APT - 1) / (ABLK * APT);
        binA_k<<<ablocks, ABLK, 0, stream>>>(src, dst, E, nbins, cursor, bpk);
        build_k<<<nbins, BBLK, 0, stream>>>(cursor, bpk, x, sorted, row_start, row_cnt, dinv, y8, n);
        int g64 = (n + 63) / 64;
        gath1_mlp_k<<<g64, 256, 0, stream>>>(sorted, row_start, row_cnt, y8, dinv, W1, b1, W2, gy, n);
        gath2_final_k<<<g64, 256, 0, stream>>>(sorted, row_start, row_cnt, gy, dinv, b2, out, n);
    } else {
        const int BLK = 256;
        const int ngrid = (n + BLK - 1) / BLK;
        const int egrid = (E + BLK - 1) / BLK;
        int*   cnt    = (int*)d_ws;
        int*   bucket = cnt + n;
        float* dinv   = (float*)(bucket + (size_t)CAP * n);
        float* y      = dinv + n;
        float* g      = y + 5 * (size_t)n;
        float* gy     = g + 2 * (size_t)n;
        hipMemsetAsync(cnt, 0, (size_t)n * sizeof(int), stream);
        fill_k<<<egrid, BLK, 0, stream>>>(src, dst, E, n, cnt, bucket);
        dinv_y_k<<<ngrid, BLK, 0, stream>>>(x, cnt, dinv, y, n);
        gather1_mlp_k<<<ngrid, BLK, 0, stream>>>(x, y, dinv, cnt, bucket, n, W1, b1, W2, g, gy);
        gather2_final_fb_k<<<ngrid, BLK, 0, stream>>>(g, gy, dinv, cnt, bucket, n, b2, out);
    }
}

// Round 10
// 62.978 us; speedup vs baseline: 5.4523x; 1.0527x over previous
//
#include <hip/hip_runtime.h>

// AttentionGCN on MI355X.
// Math: softmax over axis-of-size-1 == 1 -> h == x (aff_w/cog_w dead).
//   L1: aggregate in 5-dim input space (scatter commutes with W1).
//   L2: apply W2 first, aggregate in 2-dim output space.
// R4: counting-sort -> per-node CSR -> atomic-free gathers (127 -> 76us).
// R5: occupancy push (76 -> 68us). R6 FAILED. R7 cooperative fusion FAILED HARD
// (grid.sync spin). R8: algebraic trims (68.3 -> 66.3us).
// R9: binA sorts its chunk by bin in LDS -> coalesced bpk dump (was 64-way
//     divergent stores/wave); gathers use 8 lanes/node (serial depth 4->2).

#define NPB     256         // nodes per bin
#define BSHIFT  8
#define BINCAP  6144        // mean edges/bin ~4092, sigma ~64 -> +32 sigma headroom
#define MAXBINS 512
#define ABLK    512         // binA block threads
#define APT     8           // edges per thread in binA
#define CHUNK   (ABLK * APT)
#define BBLK    512         // build block threads
#define ROUNDS  3           // BINCAP / (BBLK*4)

// ---- pass 1: counting-sort edges into 256-node bins, packed (src<<8)|dloc ----
// Block-local LDS sort by bin -> coalesced global dump.
__global__ __launch_bounds__(ABLK) void binA_k(const int* __restrict__ src, const int* __restrict__ dst,
                                               int E, int nbins, int* __restrict__ cursor,
                                               unsigned int* __restrict__ bpk) {
    __shared__ int hist[MAXBINS];
    __shared__ int lofs[MAXBINS];
    __shared__ int gbase[MAXBINS];
    __shared__ int wsum8[8];
    __shared__ unsigned int lpk[CHUNK];
    __shared__ unsigned short lbin[CHUNK];
    int t = threadIdx.x;
    hist[t] = 0;                       // MAXBINS == ABLK
    __syncthreads();
    int base = blockIdx.x * CHUNK;
    int s_[APT], d_[APT], r_[APT];
#pragma unroll
    for (int r = 0; r < APT / 4; ++r) {
        int j0 = base + (r * ABLK + t) * 4;
        if (j0 + 3 < E) {
            int4 s4 = *(const int4*)(src + j0);
            int4 d4 = *(const int4*)(dst + j0);
            s_[r * 4 + 0] = s4.x; s_[r * 4 + 1] = s4.y; s_[r * 4 + 2] = s4.z; s_[r * 4 + 3] = s4.w;
            d_[r * 4 + 0] = d4.x; d_[r * 4 + 1] = d4.y; d_[r * 4 + 2] = d4.z; d_[r * 4 + 3] = d4.w;
#pragma unroll
            for (int q = 0; q < 4; ++q)
                r_[r * 4 + q] = atomicAdd(&hist[d_[r * 4 + q] >> BSHIFT], 1);
        } else {
#pragma unroll
            for (int q = 0; q < 4; ++q) {
                int e = j0 + q;
                if (e < E) {
                    s_[r * 4 + q] = src[e]; d_[r * 4 + q] = dst[e];
                    r_[r * 4 + q] = atomicAdd(&hist[d_[r * 4 + q] >> BSHIFT], 1);
                } else d_[r * 4 + q] = -1;
            }
        }
    }
    __syncthreads();
    // reserve global chunks + exclusive scan of hist -> lofs
    int c = hist[t];
    gbase[t] = c ? atomicAdd(&cursor[t], c) : 0;
    int lane = t & 63, w = t >> 6;
    int v = c;
#pragma unroll
    for (int dlt = 1; dlt < 64; dlt <<= 1) {
        int u = __shfl_up(v, dlt, 64);
        if (lane >= dlt) v += u;
    }
    if (lane == 63) wsum8[w] = v;
    __syncthreads();
    int wo = 0;
#pragma unroll
    for (int k = 0; k < 8; ++k) if (k < w) wo += wsum8[k];
    lofs[t] = wo + v - c;
    __syncthreads();
    // place edges into LDS ordered by bin
#pragma unroll
    for (int q = 0; q < APT; ++q) {
        if (d_[q] >= 0) {
            int b = d_[q] >> BSHIFT;
            int idx = lofs[b] + r_[q];
            lpk[idx]  = ((unsigned int)s_[q] << 8) | (unsigned int)(d_[q] & (NPB - 1));
            lbin[idx] = (unsigned short)b;
        }
    }
    __syncthreads();
    // coalesced dump: consecutive j -> consecutive positions within each bin run
    int mblk = E - base; if (mblk > CHUNK) mblk = CHUNK;
    for (int j = t; j < mblk; j += ABLK) {
        unsigned int pk = lpk[j];
        int b = lbin[j];
        int gpos = gbase[b] + (j - lofs[b]);
        if (gpos < BINCAP) bpk[(size_t)b * BINCAP + gpos] = pk;
    }
}

// ---- pass 2: per bin, build node-sorted CSR + dinv + y8 (rank-in-register) ----
__global__ __launch_bounds__(BBLK) void build_k(const int* __restrict__ cursor,
                                                const unsigned int* __restrict__ bpk,
                                                const float* __restrict__ x,
                                                int* __restrict__ sorted,
                                                int* __restrict__ row_start,
                                                unsigned short* __restrict__ row_cnt,
                                                float* __restrict__ dinv, float* __restrict__ y8, int n) {
    __shared__ int cnt[NPB];
    __shared__ int offs[NPB];
    __shared__ int srt[BINCAP];
    __shared__ int wsum[4];
    int b = blockIdx.x, t = threadIdx.x;
    if (t < NPB) cnt[t] = 0;
    __syncthreads();
    int m = cursor[b]; if (m > BINCAP) m = BINCAP;
    const unsigned int* pk = bpk + (size_t)b * BINCAP;

    unsigned int pv[ROUNDS][4];
    int rk[ROUNDS][4];
#pragma unroll
    for (int q = 0; q < ROUNDS; ++q) {
        int j0 = q * (BBLK * 4) + t * 4;
        if (j0 + 3 < m) {
            uint4 v = *(const uint4*)(pk + j0);
            pv[q][0] = v.x; pv[q][1] = v.y; pv[q][2] = v.z; pv[q][3] = v.w;
            rk[q][0] = atomicAdd(&cnt[v.x & 255u], 1);
            rk[q][1] = atomicAdd(&cnt[v.y & 255u], 1);
            rk[q][2] = atomicAdd(&cnt[v.z & 255u], 1);
            rk[q][3] = atomicAdd(&cnt[v.w & 255u], 1);
        } else {
#pragma unroll
            for (int qq = 0; qq < 4; ++qq) {
                int j = j0 + qq;
                if (j < m) { pv[q][qq] = pk[j]; rk[q][qq] = atomicAdd(&cnt[pv[q][qq] & 255u], 1); }
                else pv[q][qq] = 0xffffffffu;
            }
        }
    }
    __syncthreads();
    int c_ = 0, v = 0;
    int lane = t & 63, w = t >> 6;
    if (t < NPB) {
        c_ = cnt[t];
        v = c_;
#pragma unroll
        for (int dlt = 1; dlt < 64; dlt <<= 1) {
            int u = __shfl_up(v, dlt, 64);
            if (lane >= dlt) v += u;
        }
        if (lane == 63) wsum[w] = v;
    }
    __syncthreads();
    if (t < NPB) {
        int wo = 0;
#pragma unroll
        for (int k = 0; k < 4; ++k) if (k < w) wo += wsum[k];
        offs[t] = wo + v - c_;
    }
    __syncthreads();
#pragma unroll
    for (int q = 0; q < ROUNDS; ++q) {
#pragma unroll
        for (int qq = 0; qq < 4; ++qq) {
            unsigned int p = pv[q][qq];
            if (p != 0xffffffffu) {
                int j0 = q * (BBLK * 4) + t * 4 + qq;
                if (j0 < m) srt[offs[p & 255u] + rk[q][qq]] = (int)(p >> 8);
            }
        }
    }
    __syncthreads();
    int gb = b * BINCAP;
    for (int j0 = t * 4; j0 + 3 < m; j0 += BBLK * 4)
        *(int4*)(sorted + gb + j0) = *(const int4*)(srt + j0);
    if (t < 4) {
        int start = m & ~3;
        int j = start + t;
        if (j < m) sorted[gb + j] = srt[j];
    }
    int i = b * NPB + t;
    if (t < NPB && i < n) {
        row_start[i] = gb + offs[t];
        row_cnt[i] = (unsigned short)c_;
        float di = rsqrtf(1.0f + (float)c_);    // ref deg = 1 + indegree
        dinv[i] = di;
#pragma unroll
        for (int k = 0; k < 5; ++k) y8[(size_t)i * 8 + k] = di * x[i * 5 + k];
    }
}

// ---- pass 3: 8 lanes per node, aggregate 5-dim + split MLP ----
// v = di*(sum_in y8[s] + y8[i]); writes only gy = di*g.
__global__ __launch_bounds__(256) void gath1_mlp_k(const int* __restrict__ sorted,
                                                   const int* __restrict__ row_start,
                                                   const unsigned short* __restrict__ row_cnt,
                                                   const float* __restrict__ y8,
                                                   const float* __restrict__ dinv,
                                                   const float* __restrict__ W1, const float* __restrict__ b1,
                                                   const float* __restrict__ W2,
                                                   float* __restrict__ gy, int n) {
    __shared__ float W1s[320], b1s[64], W2s[128];
    int t = threadIdx.x;
    { int j = t; if (j < 320) W1s[j] = W1[j]; j = t + 256; if (j < 320) W1s[j] = W1[j]; }
    if (t < 64) b1s[t] = b1[t];
    if (t >= 64 && t < 192) W2s[t - 64] = W2[t - 64];
    __syncthreads();
    int grp = t >> 3, lane = t & 7;
    int i = blockIdx.x * 32 + grp;
    if (i >= n) return;
    int st = row_start[i];
    int e  = st + row_cnt[i];
    float a0 = 0.f, a1 = 0.f, a2 = 0.f, a3 = 0.f, a4 = 0.f;
    for (int j = st + lane; j < e; j += 8) {
        int s = sorted[j];
        float4 A = *(const float4*)(y8 + (size_t)s * 8);
        a0 += A.x; a1 += A.y; a2 += A.z; a3 += A.w;
        a4 += y8[(size_t)s * 8 + 4];
    }
    a0 += __shfl_xor(a0, 1); a0 += __shfl_xor(a0, 2); a0 += __shfl_xor(a0, 4);
    a1 += __shfl_xor(a1, 1); a1 += __shfl_xor(a1, 2); a1 += __shfl_xor(a1, 4);
    a2 += __shfl_xor(a2, 1); a2 += __shfl_xor(a2, 2); a2 += __shfl_xor(a2, 4);
    a3 += __shfl_xor(a3, 1); a3 += __shfl_xor(a3, 2); a3 += __shfl_xor(a3, 4);
    a4 += __shfl_xor(a4, 1); a4 += __shfl_xor(a4, 2); a4 += __shfl_xor(a4, 4);
    // self term: di^2 * x[i] = di * y8[i] -> v = di * (a + y8[i])
    float4 S = *(const float4*)(y8 + (size_t)i * 8);
    float s4 = y8[(size_t)i * 8 + 4];
    float di = dinv[i];
    float v0 = di * (a0 + S.x);
    float v1 = di * (a1 + S.y);
    float v2 = di * (a2 + S.z);
    float v3 = di * (a3 + S.w);
    float v4 = di * (a4 + s4);
    float g0 = 0.f, g1 = 0.f;
#pragma unroll
    for (int q = 0; q < 8; ++q) {
        int jj = lane + q * 8;
        float h = b1s[jj];
        h = fmaf(v0, W1s[0 * 64 + jj], h);
        h = fmaf(v1, W1s[1 * 64 + jj], h);
        h = fmaf(v2, W1s[2 * 64 + jj], h);
        h = fmaf(v3, W1s[3 * 64 + jj], h);
        h = fmaf(v4, W1s[4 * 64 + jj], h);
        h = fmaxf(h, 0.f);
        g0 = fmaf(h, W2s[2 * jj], g0);
        g1 = fmaf(h, W2s[2 * jj + 1], g1);
    }
    g0 += __shfl_xor(g0, 1); g0 += __shfl_xor(g0, 2); g0 += __shfl_xor(g0, 4);
    g1 += __shfl_xor(g1, 1); g1 += __shfl_xor(g1, 2); g1 += __shfl_xor(g1, 4);
    if (lane == 0) {
        gy[i * 2] = di * g0; gy[i * 2 + 1] = di * g1;
    }
}

// ---- pass 4: 8 lanes per node, aggregate 2-dim + bias + log_softmax ----
// o = di*(sum_in gy[s] + gy[i]) + b2
__global__ __launch_bounds__(256) void gath2_final_k(const int* __restrict__ sorted,
                                                     const int* __restrict__ row_start,
                                                     const unsigned short* __restrict__ row_cnt,
                                                     const float* __restrict__ gy,
                                                     const float* __restrict__ dinv,
                                                     const float* __restrict__ b2,
                                                     float* __restrict__ out, int n) {
    int t = threadIdx.x;
    int grp = t >> 3, lane = t & 7;
    int i = blockIdx.x * 32 + grp;
    if (i >= n) return;
    int st = row_start[i];
    int e  = st + row_cnt[i];
    float t0 = 0.f, t1 = 0.f;
    for (int j = st + lane; j < e; j += 8) {
        int s = sorted[j];
        float2 v = *(const float2*)(gy + (size_t)s * 2);
        t0 += v.x; t1 += v.y;
    }
    t0 += __shfl_xor(t0, 1); t0 += __shfl_xor(t0, 2); t0 += __shfl_xor(t0, 4);
    t1 += __shfl_xor(t1, 1); t1 += __shfl_xor(t1, 2); t1 += __shfl_xor(t1, 4);
    if (lane == 0) {
        float2 Sg = *(const float2*)(gy + (size_t)i * 2);
        float di = dinv[i];
        float o0 = di * (t0 + Sg.x) + b2[0];
        float o1 = di * (t1 + Sg.y) + b2[1];
        float mx = fmaxf(o0, o1);
        float lse = mx + logf(expf(o0 - mx) + expf(o1 - mx));
        out[i * 2]     = o0 - lse;
        out[i * 2 + 1] = o1 - lse;
    }
}

// ---------------- fallback (R1, proven) if ws too small / shape unexpected ------
#define CAP 48
__global__ void fill_k(const int* __restrict__ src, const int* __restrict__ dst,
                       int E, int n, int* __restrict__ cnt, int* __restrict__ bucket) {
    int e = blockIdx.x * blockDim.x + threadIdx.x;
    if (e >= E) return;
    int s = src[e], d = dst[e];
    int slot = atomicAdd(&cnt[d], 1);
    if (slot < CAP) bucket[slot * n + d] = s;
}
__global__ void dinv_y_k(const float* __restrict__ x, const int* __restrict__ cnt,
                         float* __restrict__ dinv, float* __restrict__ y, int n) {
    int i = blockIdx.x * blockDim.x + threadIdx.x;
    if (i >= n) return;
    float di = rsqrtf(1.0f + (float)cnt[i]);
    dinv[i] = di;
#pragma unroll
    for (int k = 0; k < 5; ++k) y[i * 5 + k] = di * x[i * 5 + k];
}
__global__ void gather1_mlp_k(const float* __restrict__ x, const float* __restrict__ y,
                              const float* __restrict__ dinv, const int* __restrict__ cnt,
                              const int* __restrict__ bucket, int n,
                              const float* __restrict__ W1, const float* __restrict__ b1,
                              const float* __restrict__ W2,
                              float* __restrict__ g, float* __restrict__ gy) {
    __shared__ float W1s[320]; __shared__ float b1s[64]; __shared__ float W2s[128];
    int t = threadIdx.x;
    for (int j = t; j < 320; j += blockDim.x) W1s[j] = W1[j];
    if (t < 64) { b1s[t] = b1[t]; W2s[2 * t] = W2[2 * t]; W2s[2 * t + 1] = W2[2 * t + 1]; }
    __syncthreads();
    int i = blockIdx.x * blockDim.x + t;
    if (i >= n) return;
    int c = cnt[i]; if (c > CAP) c = CAP;
    float a0 = 0, a1 = 0, a2 = 0, a3 = 0, a4 = 0;
    for (int j = 0; j < c; ++j) {
        int s = bucket[j * n + i];
        const float* ys = y + s * 5;
        a0 += ys[0]; a1 += ys[1]; a2 += ys[2]; a3 += ys[3]; a4 += ys[4];
    }
    float di = dinv[i], d2 = di * di;
    float v0 = di * a0 + d2 * x[i * 5 + 0], v1 = di * a1 + d2 * x[i * 5 + 1];
    float v2 = di * a2 + d2 * x[i * 5 + 2], v3 = di * a3 + d2 * x[i * 5 + 3];
    float v4 = di * a4 + d2 * x[i * 5 + 4];
    float g0 = 0.f, g1 = 0.f;
#pragma unroll
    for (int j = 0; j < 64; ++j) {
        float h = b1s[j];
        h = fmaf(v0, W1s[j], h); h = fmaf(v1, W1s[64 + j], h); h = fmaf(v2, W1s[128 + j], h);
        h = fmaf(v3, W1s[192 + j], h); h = fmaf(v4, W1s[256 + j], h);
        h = fmaxf(h, 0.f);
        g0 = fmaf(h, W2s[2 * j], g0); g1 = fmaf(h, W2s[2 * j + 1], g1);
    }
    g[i * 2] = g0; g[i * 2 + 1] = g1;
    gy[i * 2] = di * g0; gy[i * 2 + 1] = di * g1;
}
__global__ void gather2_final_fb_k(const float* __restrict__ g, const float* __restrict__ gy,
                                   const float* __restrict__ dinv, const int* __restrict__ cnt,
                                   const int* __restrict__ bucket, int n,
                                   const float* __restrict__ b2, float* __restrict__ out) {
    int i = blockIdx.x * blockDim.x + threadIdx.x;
    if (i >= n) return;
    int c = cnt[i]; if (c > CAP) c = CAP;
    float t0 = 0.f, t1 = 0.f;
    for (int j = 0; j < c; ++j) {
        int s = bucket[j * n + i];
        t0 += gy[s * 2]; t1 += gy[s * 2 + 1];
    }
    float di = dinv[i], d2 = di * di;
    float o0 = di * t0 + d2 * g[i * 2] + b2[0];
    float o1 = di * t1 + d2 * g[i * 2 + 1] + b2[1];
    float mx = fmaxf(o0, o1);
    float lse = mx + logf(expf(o0 - mx) + expf(o1 - mx));
    out[i * 2] = o0 - lse; out[i * 2 + 1] = o1 - lse;
}
// --------------------------------------------------------------------------------

extern "C" void kernel_launch(void* const* d_in, const int* in_sizes, int n_in,
                              void* d_out, int out_size, void* d_ws, size_t ws_size,
                              hipStream_t stream) {
    const float* x  = (const float*)d_in[0];
    const int*   ei = (const int*)d_in[1];
    const float* W1 = (const float*)d_in[4];
    const float* b1 = (const float*)d_in[5];
    const float* W2 = (const float*)d_in[6];
    const float* b2 = (const float*)d_in[7];
    float* out = (float*)d_out;

    const int n = in_sizes[0] / 5;
    const int E = in_sizes[1] / 2;
    const int* src = ei;
    const int* dst = ei + E;

    const int nbins = (n + NPB - 1) >> BSHIFT;
    // layout: cursor[MAXBINS] | bpk[nbins*BINCAP] u32 | sorted[nbins*BINCAP] int |
    //         row_start[n] int | row_cnt[n] u16(pad) | dinv[n] | (align64) y8[8n] | gy[2n]
    size_t need = (size_t)MAXBINS * 4 + (size_t)nbins * BINCAP * 8 +
                  (size_t)n * (4 + 2 + 4 + 32 + 8) + 128;

    if (nbins <= MAXBINS && n < (1 << 24) && ws_size >= need) {
        int* cursor = (int*)d_ws;
        unsigned int* bpk = (unsigned int*)(cursor + MAXBINS);
        int* sorted = (int*)(bpk + (size_t)nbins * BINCAP);
        int* row_start = sorted + (size_t)nbins * BINCAP;
        unsigned short* row_cnt = (unsigned short*)(row_start + n);
        float* dinv = (float*)(row_cnt + ((n + 1) & ~1));
        uintptr_t yp = (uintptr_t)(dinv + n);
        yp = (yp + 63) & ~(uintptr_t)63;
        float* y8 = (float*)yp;
        float* gy = y8 + 8 * (size_t)n;

        hipMemsetAsync(cursor, 0, MAXBINS * sizeof(int), stream);
        int ablocks = (E + CHUNK - 1) / CHUNK;
        binA_k<<<ablocks, ABLK, 0, stream>>>(src, dst, E, nbins, cursor, bpk);
        build_k<<<nbins, BBLK, 0, stream>>>(cursor, bpk, x, sorted, row_start, row_cnt, dinv, y8, n);
        int g32 = (n + 31) / 32;
        gath1_mlp_k<<<g32, 256, 0, stream>>>(sorted, row_start, row_cnt, y8, dinv, W1, b1, W2, gy, n);
        gath2_final_k<<<g32, 256, 0, stream>>>(sorted, row_start, row_cnt, gy, dinv, b2, out, n);
    } else {
        const int BLK = 256;
        const int ngrid = (n + BLK - 1) / BLK;
        const int egrid = (E + BLK - 1) / BLK;
        int*   cnt    = (int*)d_ws;
        int*   bucket = cnt + n;
        float* dinv   = (float*)(bucket + (size_t)CAP * n);
        float* y      = dinv + n;
        float* g      = y + 5 * (size_t)n;
        float* gy     = g + 2 * (size_t)n;
        hipMemsetAsync(cnt, 0, (size_t)n * sizeof(int), stream);
        fill_k<<<egrid, BLK, 0, stream>>>(src, dst, E, n, cnt, bucket);
        dinv_y_k<<<ngrid, BLK, 0, stream>>>(x, cnt, dinv, y, n);
        gather1_mlp_k<<<ngrid, BLK, 0, stream>>>(x, y, dinv, cnt, bucket, n, W1, b1, W2, g, gy);
        gather2_final_fb_k<<<ngrid, BLK, 0, stream>>>(g, gy, dinv, cnt, bucket, n, b2, out);
    }
}

// Round 11
// 60.562 us; speedup vs baseline: 5.6699x; 1.0399x over previous
//
#include <hip/hip_runtime.h>

// AttentionGCN on MI355X.
// Math: softmax over axis-of-size-1 == 1 -> h == x (aff_w/cog_w dead).
//   L1: aggregate in 5-dim input space (scatter commutes with W1).
//   L2: apply W2 first, aggregate in 2-dim output space.
// R4: counting-sort -> per-node CSR -> atomic-free gathers (127 -> 76us).
// R5: occupancy (76->68). R6 FAILED. R7 coop-fusion FAILED HARD (grid.sync spin).
// R8: algebraic trims (68.3->66.3). R9: binA LDS-sorted coalesced dump +
//     8-lane gathers (66.3->63.0).
// R10: build_k 1024thr / BINCAP 8192 (3 -> 6.1 waves/SIMD, 2 blk/CU = full CU);
//      row metadata packed (start<<9|cnt) -> one load/node in gathers.

#define NPB     256         // nodes per bin
#define BSHIFT  8
#define BINCAP  8192        // mean edges/bin ~4092; huge headroom (ws is ~256MB)
#define MAXBINS 512
#define ABLK    512         // binA block threads
#define APT     8           // edges per thread in binA
#define CHUNK   (ABLK * APT)
#define BBLK    1024        // build block threads (16 waves, 2 blocks/CU)
#define ROUNDS  2           // BINCAP / (BBLK*4)

// ---- pass 1: counting-sort edges into 256-node bins, packed (src<<8)|dloc ----
// Block-local LDS sort by bin -> coalesced global dump. (R9, proven)
__global__ __launch_bounds__(ABLK) void binA_k(const int* __restrict__ src, const int* __restrict__ dst,
                                               int E, int nbins, int* __restrict__ cursor,
                                               unsigned int* __restrict__ bpk) {
    __shared__ int hist[MAXBINS];
    __shared__ int lofs[MAXBINS];
    __shared__ int gbase[MAXBINS];
    __shared__ int wsum8[8];
    __shared__ unsigned int lpk[CHUNK];
    __shared__ unsigned short lbin[CHUNK];
    int t = threadIdx.x;
    hist[t] = 0;                       // MAXBINS == ABLK
    __syncthreads();
    int base = blockIdx.x * CHUNK;
    int s_[APT], d_[APT], r_[APT];
#pragma unroll
    for (int r = 0; r < APT / 4; ++r) {
        int j0 = base + (r * ABLK + t) * 4;
        if (j0 + 3 < E) {
            int4 s4 = *(const int4*)(src + j0);
            int4 d4 = *(const int4*)(dst + j0);
            s_[r * 4 + 0] = s4.x; s_[r * 4 + 1] = s4.y; s_[r * 4 + 2] = s4.z; s_[r * 4 + 3] = s4.w;
            d_[r * 4 + 0] = d4.x; d_[r * 4 + 1] = d4.y; d_[r * 4 + 2] = d4.z; d_[r * 4 + 3] = d4.w;
#pragma unroll
            for (int q = 0; q < 4; ++q)
                r_[r * 4 + q] = atomicAdd(&hist[d_[r * 4 + q] >> BSHIFT], 1);
        } else {
#pragma unroll
            for (int q = 0; q < 4; ++q) {
                int e = j0 + q;
                if (e < E) {
                    s_[r * 4 + q] = src[e]; d_[r * 4 + q] = dst[e];
                    r_[r * 4 + q] = atomicAdd(&hist[d_[r * 4 + q] >> BSHIFT], 1);
                } else d_[r * 4 + q] = -1;
            }
        }
    }
    __syncthreads();
    // reserve global chunks + exclusive scan of hist -> lofs
    int c = hist[t];
    gbase[t] = c ? atomicAdd(&cursor[t], c) : 0;
    int lane = t & 63, w = t >> 6;
    int v = c;
#pragma unroll
    for (int dlt = 1; dlt < 64; dlt <<= 1) {
        int u = __shfl_up(v, dlt, 64);
        if (lane >= dlt) v += u;
    }
    if (lane == 63) wsum8[w] = v;
    __syncthreads();
    int wo = 0;
#pragma unroll
    for (int k = 0; k < 8; ++k) if (k < w) wo += wsum8[k];
    lofs[t] = wo + v - c;
    __syncthreads();
    // place edges into LDS ordered by bin
#pragma unroll
    for (int q = 0; q < APT; ++q) {
        if (d_[q] >= 0) {
            int b = d_[q] >> BSHIFT;
            int idx = lofs[b] + r_[q];
            lpk[idx]  = ((unsigned int)s_[q] << 8) | (unsigned int)(d_[q] & (NPB - 1));
            lbin[idx] = (unsigned short)b;
        }
    }
    __syncthreads();
    // coalesced dump: consecutive j -> consecutive positions within each bin run
    int mblk = E - base; if (mblk > CHUNK) mblk = CHUNK;
    for (int j = t; j < mblk; j += ABLK) {
        unsigned int pk = lpk[j];
        int b = lbin[j];
        int gpos = gbase[b] + (j - lofs[b]);
        if (gpos < BINCAP) bpk[(size_t)b * BINCAP + gpos] = pk;
    }
}

// ---- pass 2: per bin, node-sorted CSR + dinv + y8; 1024 threads, 2 blk/CU ----
__global__ __launch_bounds__(BBLK) void build_k(const int* __restrict__ cursor,
                                                const unsigned int* __restrict__ bpk,
                                                const float* __restrict__ x,
                                                int* __restrict__ sorted,
                                                unsigned int* __restrict__ rowmeta,
                                                float* __restrict__ dinv, float* __restrict__ y8, int n) {
    __shared__ int cnt[NPB];
    __shared__ int offs[NPB];
    __shared__ int srt[BINCAP];
    __shared__ int wsum[4];
    int b = blockIdx.x, t = threadIdx.x;
    if (t < NPB) cnt[t] = 0;
    __syncthreads();
    int m = cursor[b]; if (m > BINCAP) m = BINCAP;
    const unsigned int* pk = bpk + (size_t)b * BINCAP;

    unsigned int pv[ROUNDS][4];
    int rk[ROUNDS][4];
#pragma unroll
    for (int q = 0; q < ROUNDS; ++q) {
        int j0 = q * (BBLK * 4) + t * 4;
        if (j0 + 3 < m) {
            uint4 v = *(const uint4*)(pk + j0);
            pv[q][0] = v.x; pv[q][1] = v.y; pv[q][2] = v.z; pv[q][3] = v.w;
            rk[q][0] = atomicAdd(&cnt[v.x & 255u], 1);
            rk[q][1] = atomicAdd(&cnt[v.y & 255u], 1);
            rk[q][2] = atomicAdd(&cnt[v.z & 255u], 1);
            rk[q][3] = atomicAdd(&cnt[v.w & 255u], 1);
        } else {
#pragma unroll
            for (int qq = 0; qq < 4; ++qq) {
                int j = j0 + qq;
                if (j < m) { pv[q][qq] = pk[j]; rk[q][qq] = atomicAdd(&cnt[pv[q][qq] & 255u], 1); }
                else pv[q][qq] = 0xffffffffu;
            }
        }
    }
    __syncthreads();
    // exclusive scan of cnt[0..255] by first 256 threads (4 waves)
    int c_ = 0, v = 0;
    int lane = t & 63, w = t >> 6;
    if (t < NPB) {
        c_ = cnt[t];
        v = c_;
#pragma unroll
        for (int dlt = 1; dlt < 64; dlt <<= 1) {
            int u = __shfl_up(v, dlt, 64);
            if (lane >= dlt) v += u;
        }
        if (lane == 63) wsum[w] = v;
    }
    __syncthreads();
    int gb = b * BINCAP;
    if (t < NPB) {
        int wo = 0;
#pragma unroll
        for (int k = 0; k < 4; ++k) if (k < w) wo += wsum[k];
        int offs_t = wo + v - c_;
        offs[t] = offs_t;
        int i = b * NPB + t;
        if (i < n) {
            int cc = c_ < 511 ? c_ : 511;
            rowmeta[i] = ((unsigned int)(gb + offs_t) << 9) | (unsigned int)cc;
            float di = rsqrtf(1.0f + (float)c_);    // ref deg = 1 + indegree
            dinv[i] = di;
#pragma unroll
            for (int k = 0; k < 5; ++k) y8[(size_t)i * 8 + k] = di * x[i * 5 + k];
        }
    }
    __syncthreads();
    // scatter into LDS at unique positions (no atomics)
#pragma unroll
    for (int q = 0; q < ROUNDS; ++q) {
#pragma unroll
        for (int qq = 0; qq < 4; ++qq) {
            unsigned int p = pv[q][qq];
            if (p != 0xffffffffu) {
                int j0 = q * (BBLK * 4) + t * 4 + qq;
                if (j0 < m) srt[offs[p & 255u] + rk[q][qq]] = (int)(p >> 8);
            }
        }
    }
    __syncthreads();
    // coalesced dump of sorted srcs
    for (int j0 = t * 4; j0 + 3 < m; j0 += BBLK * 4)
        *(int4*)(sorted + gb + j0) = *(const int4*)(srt + j0);
    if (t < 4) {
        int start = m & ~3;
        int j = start + t;
        if (j < m) sorted[gb + j] = srt[j];
    }
}

// ---- pass 3: 8 lanes per node, aggregate 5-dim + split MLP ----
// v = di*(sum_in y8[s] + y8[i]); writes only gy = di*g.
__global__ __launch_bounds__(256) void gath1_mlp_k(const int* __restrict__ sorted,
                                                   const unsigned int* __restrict__ rowmeta,
                                                   const float* __restrict__ y8,
                                                   const float* __restrict__ dinv,
                                                   const float* __restrict__ W1, const float* __restrict__ b1,
                                                   const float* __restrict__ W2,
                                                   float* __restrict__ gy, int n) {
    __shared__ float W1s[320], b1s[64], W2s[128];
    int t = threadIdx.x;
    { int j = t; if (j < 320) W1s[j] = W1[j]; j = t + 256; if (j < 320) W1s[j] = W1[j]; }
    if (t < 64) b1s[t] = b1[t];
    if (t >= 64 && t < 192) W2s[t - 64] = W2[t - 64];
    __syncthreads();
    int grp = t >> 3, lane = t & 7;
    int i = blockIdx.x * 32 + grp;
    if (i >= n) return;
    unsigned int meta = rowmeta[i];
    int st = (int)(meta >> 9);
    int e  = st + (int)(meta & 511u);
    float a0 = 0.f, a1 = 0.f, a2 = 0.f, a3 = 0.f, a4 = 0.f;
    for (int j = st + lane; j < e; j += 8) {
        int s = sorted[j];
        float4 A = *(const float4*)(y8 + (size_t)s * 8);
        a0 += A.x; a1 += A.y; a2 += A.z; a3 += A.w;
        a4 += y8[(size_t)s * 8 + 4];
    }
    a0 += __shfl_xor(a0, 1); a0 += __shfl_xor(a0, 2); a0 += __shfl_xor(a0, 4);
    a1 += __shfl_xor(a1, 1); a1 += __shfl_xor(a1, 2); a1 += __shfl_xor(a1, 4);
    a2 += __shfl_xor(a2, 1); a2 += __shfl_xor(a2, 2); a2 += __shfl_xor(a2, 4);
    a3 += __shfl_xor(a3, 1); a3 += __shfl_xor(a3, 2); a3 += __shfl_xor(a3, 4);
    a4 += __shfl_xor(a4, 1); a4 += __shfl_xor(a4, 2); a4 += __shfl_xor(a4, 4);
    // self term: di^2 * x[i] = di * y8[i] -> v = di * (a + y8[i])
    float4 S = *(const float4*)(y8 + (size_t)i * 8);
    float s4 = y8[(size_t)i * 8 + 4];
    float di = dinv[i];
    float v0 = di * (a0 + S.x);
    float v1 = di * (a1 + S.y);
    float v2 = di * (a2 + S.z);
    float v3 = di * (a3 + S.w);
    float v4 = di * (a4 + s4);
    float g0 = 0.f, g1 = 0.f;
#pragma unroll
    for (int q = 0; q < 8; ++q) {
        int jj = lane + q * 8;
        float h = b1s[jj];
        h = fmaf(v0, W1s[0 * 64 + jj], h);
        h = fmaf(v1, W1s[1 * 64 + jj], h);
        h = fmaf(v2, W1s[2 * 64 + jj], h);
        h = fmaf(v3, W1s[3 * 64 + jj], h);
        h = fmaf(v4, W1s[4 * 64 + jj], h);
        h = fmaxf(h, 0.f);
        g0 = fmaf(h, W2s[2 * jj], g0);
        g1 = fmaf(h, W2s[2 * jj + 1], g1);
    }
    g0 += __shfl_xor(g0, 1); g0 += __shfl_xor(g0, 2); g0 += __shfl_xor(g0, 4);
    g1 += __shfl_xor(g1, 1); g1 += __shfl_xor(g1, 2); g1 += __shfl_xor(g1, 4);
    if (lane == 0) {
        gy[i * 2] = di * g0; gy[i * 2 + 1] = di * g1;
    }
}

// ---- pass 4: 8 lanes per node, aggregate 2-dim + bias + log_softmax ----
// o = di*(sum_in gy[s] + gy[i]) + b2
__global__ __launch_bounds__(256) void gath2_final_k(const int* __restrict__ sorted,
                                                     const unsigned int* __restrict__ rowmeta,
                                                     const float* __restrict__ gy,
                                                     const float* __restrict__ dinv,
                                                     const float* __restrict__ b2,
                                                     float* __restrict__ out, int n) {
    int t = threadIdx.x;
    int grp = t >> 3, lane = t & 7;
    int i = blockIdx.x * 32 + grp;
    if (i >= n) return;
    unsigned int meta = rowmeta[i];
    int st = (int)(meta >> 9);
    int e  = st + (int)(meta & 511u);
    float t0 = 0.f, t1 = 0.f;
    for (int j = st + lane; j < e; j += 8) {
        int s = sorted[j];
        float2 v = *(const float2*)(gy + (size_t)s * 2);
        t0 += v.x; t1 += v.y;
    }
    t0 += __shfl_xor(t0, 1); t0 += __shfl_xor(t0, 2); t0 += __shfl_xor(t0, 4);
    t1 += __shfl_xor(t1, 1); t1 += __shfl_xor(t1, 2); t1 += __shfl_xor(t1, 4);
    if (lane == 0) {
        float2 Sg = *(const float2*)(gy + (size_t)i * 2);
        float di = dinv[i];
        float o0 = di * (t0 + Sg.x) + b2[0];
        float o1 = di * (t1 + Sg.y) + b2[1];
        float mx = fmaxf(o0, o1);
        float lse = mx + logf(expf(o0 - mx) + expf(o1 - mx));
        out[i * 2]     = o0 - lse;
        out[i * 2 + 1] = o1 - lse;
    }
}

// ---------------- fallback (R1, proven) if ws too small / shape unexpected ------
#define CAP 48
__global__ void fill_k(const int* __restrict__ src, const int* __restrict__ dst,
                       int E, int n, int* __restrict__ cnt, int* __restrict__ bucket) {
    int e = blockIdx.x * blockDim.x + threadIdx.x;
    if (e >= E) return;
    int s = src[e], d = dst[e];
    int slot = atomicAdd(&cnt[d], 1);
    if (slot < CAP) bucket[slot * n + d] = s;
}
__global__ void dinv_y_k(const float* __restrict__ x, const int* __restrict__ cnt,
                         float* __restrict__ dinv, float* __restrict__ y, int n) {
    int i = blockIdx.x * blockDim.x + threadIdx.x;
    if (i >= n) return;
    float di = rsqrtf(1.0f + (float)cnt[i]);
    dinv[i] = di;
#pragma unroll
    for (int k = 0; k < 5; ++k) y[i * 5 + k] = di * x[i * 5 + k];
}
__global__ void gather1_mlp_k(const float* __restrict__ x, const float* __restrict__ y,
                              const float* __restrict__ dinv, const int* __restrict__ cnt,
                              const int* __restrict__ bucket, int n,
                              const float* __restrict__ W1, const float* __restrict__ b1,
                              const float* __restrict__ W2,
                              float* __restrict__ g, float* __restrict__ gy) {
    __shared__ float W1s[320]; __shared__ float b1s[64]; __shared__ float W2s[128];
    int t = threadIdx.x;
    for (int j = t; j < 320; j += blockDim.x) W1s[j] = W1[j];
    if (t < 64) { b1s[t] = b1[t]; W2s[2 * t] = W2[2 * t]; W2s[2 * t + 1] = W2[2 * t + 1]; }
    __syncthreads();
    int i = blockIdx.x * blockDim.x + t;
    if (i >= n) return;
    int c = cnt[i]; if (c > CAP) c = CAP;
    float a0 = 0, a1 = 0, a2 = 0, a3 = 0, a4 = 0;
    for (int j = 0; j < c; ++j) {
        int s = bucket[j * n + i];
        const float* ys = y + s * 5;
        a0 += ys[0]; a1 += ys[1]; a2 += ys[2]; a3 += ys[3]; a4 += ys[4];
    }
    float di = dinv[i], d2 = di * di;
    float v0 = di * a0 + d2 * x[i * 5 + 0], v1 = di * a1 + d2 * x[i * 5 + 1];
    float v2 = di * a2 + d2 * x[i * 5 + 2], v3 = di * a3 + d2 * x[i * 5 + 3];
    float v4 = di * a4 + d2 * x[i * 5 + 4];
    float g0 = 0.f, g1 = 0.f;
#pragma unroll
    for (int j = 0; j < 64; ++j) {
        float h = b1s[j];
        h = fmaf(v0, W1s[j], h); h = fmaf(v1, W1s[64 + j], h); h = fmaf(v2, W1s[128 + j], h);
        h = fmaf(v3, W1s[192 + j], h); h = fmaf(v4, W1s[256 + j], h);
        h = fmaxf(h, 0.f);
        g0 = fmaf(h, W2s[2 * j], g0); g1 = fmaf(h, W2s[2 * j + 1], g1);
    }
    g[i * 2] = g0; g[i * 2 + 1] = g1;
    gy[i * 2] = di * g0; gy[i * 2 + 1] = di * g1;
}
__global__ void gather2_final_fb_k(const float* __restrict__ g, const float* __restrict__ gy,
                                   const float* __restrict__ dinv, const int* __restrict__ cnt,
                                   const int* __restrict__ bucket, int n,
                                   const float* __restrict__ b2, float* __restrict__ out) {
    int i = blockIdx.x * blockDim.x + threadIdx.x;
    if (i >= n) return;
    int c = cnt[i]; if (c > CAP) c = CAP;
    float t0 = 0.f, t1 = 0.f;
    for (int j = 0; j < c; ++j) {
        int s = bucket[j * n + i];
        t0 += gy[s * 2]; t1 += gy[s * 2 + 1];
    }
    float di = dinv[i], d2 = di * di;
    float o0 = di * t0 + d2 * g[i * 2] + b2[0];
    float o1 = di * t1 + d2 * g[i * 2 + 1] + b2[1];
    float mx = fmaxf(o0, o1);
    float lse = mx + logf(expf(o0 - mx) + expf(o1 - mx));
    out[i * 2] = o0 - lse; out[i * 2 + 1] = o1 - lse;
}
// --------------------------------------------------------------------------------

extern "C" void kernel_launch(void* const* d_in, const int* in_sizes, int n_in,
                              void* d_out, int out_size, void* d_ws, size_t ws_size,
                              hipStream_t stream) {
    const float* x  = (const float*)d_in[0];
    const int*   ei = (const int*)d_in[1];
    const float* W1 = (const float*)d_in[4];
    const float* b1 = (const float*)d_in[5];
    const float* W2 = (const float*)d_in[6];
    const float* b2 = (const float*)d_in[7];
    float* out = (float*)d_out;

    const int n = in_sizes[0] / 5;
    const int E = in_sizes[1] / 2;
    const int* src = ei;
    const int* dst = ei + E;

    const int nbins = (n + NPB - 1) >> BSHIFT;
    // layout: cursor[MAXBINS] | bpk[nbins*BINCAP] u32 | sorted[nbins*BINCAP] int |
    //         rowmeta[n] u32 | dinv[n] | (align64) y8[8n] | gy[2n]
    size_t need = (size_t)MAXBINS * 4 + (size_t)nbins * BINCAP * 8 +
                  (size_t)n * (4 + 4 + 32 + 8) + 128;

    if (nbins <= MAXBINS && n < (1 << 23) && ws_size >= need) {
        int* cursor = (int*)d_ws;
        unsigned int* bpk = (unsigned int*)(cursor + MAXBINS);
        int* sorted = (int*)(bpk + (size_t)nbins * BINCAP);
        unsigned int* rowmeta = (unsigned int*)(sorted + (size_t)nbins * BINCAP);
        float* dinv = (float*)(rowmeta + n);
        uintptr_t yp = (uintptr_t)(dinv + n);
        yp = (yp + 63) & ~(uintptr_t)63;
        float* y8 = (float*)yp;
        float* gy = y8 + 8 * (size_t)n;

        hipMemsetAsync(cursor, 0, MAXBINS * sizeof(int), stream);
        int ablocks = (E + CHUNK - 1) / CHUNK;
        binA_k<<<ablocks, ABLK, 0, stream>>>(src, dst, E, nbins, cursor, bpk);
        build_k<<<nbins, BBLK, 0, stream>>>(cursor, bpk, x, sorted, rowmeta, dinv, y8, n);
        int g32 = (n + 31) / 32;
        gath1_mlp_k<<<g32, 256, 0, stream>>>(sorted, rowmeta, y8, dinv, W1, b1, W2, gy, n);
        gath2_final_k<<<g32, 256, 0, stream>>>(sorted, rowmeta, gy, dinv, b2, out, n);
    } else {
        const int BLK = 256;
        const int ngrid = (n + BLK - 1) / BLK;
        const int egrid = (E + BLK - 1) / BLK;
        int*   cnt    = (int*)d_ws;
        int*   bucket = cnt + n;
        float* dinv   = (float*)(bucket + (size_t)CAP * n);
        float* y      = dinv + n;
        float* g      = y + 5 * (size_t)n;
        float* gy     = g + 2 * (size_t)n;
        hipMemsetAsync(cnt, 0, (size_t)n * sizeof(int), stream);
        fill_k<<<egrid, BLK, 0, stream>>>(src, dst, E, n, cnt, bucket);
        dinv_y_k<<<ngrid, BLK, 0, stream>>>(x, cnt, dinv, y, n);
        gather1_mlp_k<<<ngrid, BLK, 0, stream>>>(x, y, dinv, cnt, bucket, n, W1, b1, W2, g, gy);
        gather2_final_fb_k<<<ngrid, BLK, 0, stream>>>(g, gy, dinv, cnt, bucket, n, b2, out);
    }
}